// Round 6
// baseline (299.203 us; speedup 1.0000x reference)
//
#include <hip/hip_runtime.h>
#include <hip/hip_bf16.h>
#include <stdint.h>

#define DEV __device__ __forceinline__

typedef __attribute__((ext_vector_type(8))) short short8;    // 8 bf16 (MFMA A/B frag)
typedef __attribute__((ext_vector_type(4))) float floatx4;   // MFMA C/D frag

constexpr int TM  = 64;     // rows per block
constexpr int NB  = 131072; // batch
constexpr int AST = 264;    // act row stride (bf16 elems)

struct F4 { float x,y,z,w; };   // 4-byte-aligned float4 (x rows are odd-strided)

// ---- packed bf16 weight layout in d_ws (element offsets) ----
// A=weights, B=activations. Wave w owns a 64-col (L1/L2), 32-col (L3) n-slice.
constexpr int OFF_W1 = 0;        // 4w x 7kc x 4nt x 512   (K=224: 199 state + td@199 + BIAS@200)
constexpr int OFF_W2 = 57344;    // 4w x 8 x 4 x 512       (K=256, N=256)
constexpr int OFF_W3 = 122880;   // 4w x 8 x 2 x 512       (K=256, N=128)
constexpr int OFF_WH = 155648;   // 4h x 4 x 4 x 512       (K=128, N=64; h=0..2 adv, h=3 value)
constexpr int OFF_WA2= 188416;   // 3h x 2 x 2 x 512       (K=64,  N=32)
constexpr int NWQ    = 194560;

// cq layout: all float4-loadable bases 16B-aligned
constexpr int C_B1=0, C_G1=256, C_BE1=512, C_B2=768, C_G2=1024, C_BE2=1280,
  C_B3=1536, C_G3=1664, C_BE3=1792, C_BV1=1920, C_GV=1984, C_BEV=2048,
  C_WV2=2112, C_BV2=2176, C_BA1=2180, C_GA=2372, C_BEA=2564, C_BA2=2756;
constexpr int NCONST=2852;

struct Ptrs {
  const float *state,*td,*W1,*b1,*g1,*be1,*W2,*b2,*g2,*be2,*W3,*b3,*g3,*be3,
    *Wv1,*bv1,*gv,*bev,*Wv2,*bv2,*Wa1,*ba1,*ga,*bea,*Wa2,*ba2;
  const int *et;
};

DEV unsigned short f2bf(float x){
  uint32_t u = __float_as_uint(x);
  u += 0x7fffu + ((u>>16)&1u);
  return (unsigned short)(u>>16);
}
DEV uint32_t pkbf(float a, float b){
  float2 f2; f2.x=a; f2.y=b;
  __hip_bfloat162 h = __float22bfloat162_rn(f2);
  union { __hip_bfloat162 h; uint32_t u; } cv; cv.h = h;
  return cv.u;
}

// =====================================================================
// prep: quantize + transpose + pack weights (W1 carries b1 at k==200)
// (verified R1 packing + verified R1 cq table — DO NOT TOUCH)
// =====================================================================
__global__ void prep_kernel(Ptrs p, unsigned short* __restrict__ wq, float* __restrict__ cq){
  int idx = blockIdx.x*256 + threadIdx.x;
  if (idx < NWQ) {
    float v = 0.f;
    if (idx < OFF_W2) {                       // W1 (+bias row at k=200)
      int e = idx, w = e/14336, r = e%14336;
      int kc = r>>11, ct=(r>>9)&3, l=(r>>3)&63, j=r&7;
      int n = w*64 + ct*16 + (l&15);
      int k = kc*32 + (l>>4)*8 + j;
      if (k < 200) v = p.W1[k*256 + n];
      else if (k == 200) v = p.b1[n];
    } else if (idx < OFF_W3) {                // W2
      int e = idx-OFF_W2, w=e>>14, r=e&16383;
      int kc=r>>11, ct=(r>>9)&3, l=(r>>3)&63, j=r&7;
      int n = w*64 + ct*16 + (l&15);
      int k = kc*32 + (l>>4)*8 + j;
      v = p.W2[k*256 + n];
    } else if (idx < OFF_WH) {                // W3
      int e = idx-OFF_W3, w=e>>13, r=e&8191;
      int kc=r>>10, ct=(r>>9)&1, l=(r>>3)&63, j=r&7;
      int n = w*32 + ct*16 + (l&15);
      int k = kc*32 + (l>>4)*8 + j;
      v = p.W3[k*128 + n];
    } else if (idx < OFF_WA2) {               // Wv1/Wa1
      int e = idx-OFF_WH, h=e>>13, r=e&8191;
      int kc=r>>11, ct=(r>>9)&3, l=(r>>3)&63, j=r&7;
      int n = ct*16 + (l&15);
      int k = kc*32 + (l>>4)*8 + j;
      v = (h<3) ? p.Wa1[h*8192 + k*64 + n] : p.Wv1[k*64 + n];
    } else {                                  // Wa2
      int e = idx-OFF_WA2, h=e>>11, r=e&2047;
      int kc=r>>10, ct=(r>>9)&1, l=(r>>3)&63, j=r&7;
      int n = ct*16 + (l&15);
      int k = kc*32 + (l>>4)*8 + j;
      v = p.Wa2[h*2048 + k*32 + n];
    }
    wq[idx] = f2bf(v);
  } else if (idx < NWQ + NCONST) {
    int ci = idx - NWQ;
    float v;
    if      (ci < 256)  v = p.b1[ci];
    else if (ci < 512)  v = p.g1[ci-256];
    else if (ci < 768)  v = p.be1[ci-512];
    else if (ci < 1024) v = p.b2[ci-768];
    else if (ci < 1280) v = p.g2[ci-1024];
    else if (ci < 1536) v = p.be2[ci-1280];
    else if (ci < 1664) v = p.b3[ci-1536];
    else if (ci < 1792) v = p.g3[ci-1664];
    else if (ci < 1920) v = p.be3[ci-1792];
    else if (ci < 1984) v = p.bv1[ci-1920];
    else if (ci < 2048) v = p.gv[ci-1984];
    else if (ci < 2112) v = p.bev[ci-2048];
    else if (ci < 2176) v = p.Wv2[ci-2112];
    else if (ci < 2180) v = (ci==2176) ? p.bv2[0] : 0.f;   // bv2 + pad
    else if (ci < 2372) v = p.ba1[ci-2180];
    else if (ci < 2564) v = p.ga[ci-2372];
    else if (ci < 2756) v = p.bea[ci-2564];
    else                v = p.ba2[ci-2756];
    cq[ci] = v;
  }
}

// =====================================================================
// device helpers. C layout: col = batch row (lane&15), row = n = q*4+reg.
// =====================================================================
template<int RT>
DEV void zeroAccT(floatx4 (&acc)[RT][4]){
  const floatx4 z = {0.f,0.f,0.f,0.f};
  #pragma unroll
  for (int rt=0;rt<RT;rt++)
    #pragma unroll
    for (int ct=0;ct<4;ct++) acc[rt][ct]=z;
}

// software-pipelined GEMM with cross-barrier prefetched first 4 weight frags.
// frag linear index i = kc*RT + rt; pf holds i=0..3 (PFK=4/RT kc's worth).
template<int KC,int RT>
DEV void runGemmPF(floatx4 (&acc)[RT][4], const unsigned short* __restrict__ wp,
                   const unsigned short* __restrict__ aB, int aOff, int lane,
                   const short8 (&pf)[4]){
  constexpr int PFK = 4/RT;               // kc's per 4-frag group
  constexpr int NBLK = KC/PFK;
  short8 wcur[4];
  #pragma unroll
  for (int i=0;i<4;i++) wcur[i]=pf[i];
  #pragma unroll
  for (int blk=0; blk<NBLK; blk++){
    short8 wnxt[4];
    if (blk+1 < NBLK){
      #pragma unroll
      for (int i=0;i<4;i++)
        wnxt[i] = *(const short8*)(wp + ((blk+1)*4 + i)*512 + lane*8);
    }
    #pragma unroll
    for (int kk=0;kk<PFK;kk++){
      const int kc = blk*PFK+kk;
      short8 a[4];
      #pragma unroll
      for (int c=0;c<4;c++)
        a[c] = *(const short8*)(aB + c*16*AST + aOff + kc*32);
      #pragma unroll
      for (int rt=0;rt<RT;rt++)
        #pragma unroll
        for (int c=0;c<4;c++)
          acc[rt][c] = __builtin_amdgcn_mfma_f32_16x16x32_bf16(wcur[kk*RT+rt], a[c], acc[rt][c], 0,0,0);
    }
    #pragma unroll
    for (int i=0;i<4;i++) wcur[i]=wnxt[i];
  }
}

// small non-pipelined GEMM (a2)
template<int KC,int RT>
DEV void runGemmW(floatx4 (&acc)[RT][4], const unsigned short* __restrict__ wp,
                  const unsigned short* __restrict__ aB, int aOff, int lane){
  #pragma unroll
  for (int kc=0;kc<KC;kc++){
    short8 a[4];
    #pragma unroll
    for (int c=0;c<4;c++)
      a[c] = *(const short8*)(aB + c*16*AST + aOff + kc*32);
    #pragma unroll
    for (int rt=0;rt<RT;rt++){
      short8 bw = *(const short8*)(wp + (kc*RT+rt)*512 + lane*8);
      #pragma unroll
      for (int c=0;c<4;c++)
        acc[rt][c] = __builtin_amdgcn_mfma_f32_16x16x32_bf16(bw, a[c], acc[rt][c], 0,0,0);
    }
  }
}

// L1 GEMM, pipelined, B-frags built directly from global x (verified in R4b).
DEV void gemmL1Gpf(floatx4 (&acc)[4][4], const unsigned short* __restrict__ wp,
                   const float* __restrict__ xb, const float* __restrict__ tdp,
                   int lane, const short8 (&pf)[4]){
  const int q=lane>>4, ln=lane&15;
  short8 wcur[4];
  #pragma unroll
  for (int i=0;i<4;i++) wcur[i]=pf[i];
  #pragma unroll
  for (int kc=0;kc<7;kc++){
    short8 wnxt[4];
    if (kc<6){
      #pragma unroll
      for (int rt=0;rt<4;rt++)
        wnxt[rt] = *(const short8*)(wp + ((kc+1)*4+rt)*512 + lane*8);
    }
    short8 bfr[4];
    #pragma unroll
    for (int ct=0;ct<4;ct++){
      const float* rp = xb + (size_t)(ct*16+ln)*199;
      uint32_t w0,w1,w2,w3;
      if (kc<6){
        F4 lo = *(const F4*)(rp + kc*32 + q*8);
        F4 hi = *(const F4*)(rp + kc*32 + q*8 + 4);
        w0=pkbf(lo.x,lo.y); w1=pkbf(lo.z,lo.w); w2=pkbf(hi.x,hi.y); w3=pkbf(hi.z,hi.w);
      } else if (q==0){                      // k=192..198 + td@199
        F4 lo = *(const F4*)(rp + 192);
        float v4=rp[196], v5=rp[197], v6=rp[198], v7=tdp[ct*16+ln];
        w0=pkbf(lo.x,lo.y); w1=pkbf(lo.z,lo.w); w2=pkbf(v4,v5); w3=pkbf(v6,v7);
      } else if (q==1){                      // k=200 -> 1.0 (b1 row), rest 0
        w0=0x3F80u; w1=0u; w2=0u; w3=0u;
      } else {
        w0=0u; w1=0u; w2=0u; w3=0u;
      }
      union { uint32_t u[4]; short8 s; } cv;
      cv.u[0]=w0; cv.u[1]=w1; cv.u[2]=w2; cv.u[3]=w3;
      bfr[ct]=cv.s;
    }
    #pragma unroll
    for (int rt=0;rt<4;rt++)
      #pragma unroll
      for (int c=0;c<4;c++)
        acc[rt][c] = __builtin_amdgcn_mfma_f32_16x16x32_bf16(wcur[rt], bfr[c], acc[rt][c], 0,0,0);
    #pragma unroll
    for (int i=0;i<4;i++) wcur[i]=wnxt[i];
  }
}

// bias fold + per-batch-row (s,ss) -> per-wave slot store (no atomics, no init)
template<int RT,bool BIAS>
DEV void statsS(floatx4 (&acc)[RT][4], const float* __restrict__ cq, int bo,
                float (*sst)[64][4], int w, int q, int ln){
  if constexpr (BIAS){
    #pragma unroll
    for (int rt=0;rt<RT;rt++){
      floatx4 b4 = *(const floatx4*)(cq + bo + rt*16 + q*4);
      #pragma unroll
      for (int ct=0;ct<4;ct++) acc[rt][ct] += b4;
    }
  }
  #pragma unroll
  for (int ct=0;ct<4;ct++){
    float s=0.f, ss=0.f;
    #pragma unroll
    for (int rt=0;rt<RT;rt++)
      #pragma unroll
      for (int r=0;r<4;r++){ float v=acc[rt][ct][r]; s+=v; ss+=v*v; }
    s += __shfl_xor(s,16); ss += __shfl_xor(ss,16);
    s += __shfl_xor(s,32); ss += __shfl_xor(ss,32);
    if (q==0){
      sst[0][ct*16+ln][w] = s;
      sst[1][ct*16+ln][w] = ss;
    }
  }
}

// LN apply + relu + natural-order packed bf16 write; sums 4 per-wave partials
template<int RT>
DEV void lnWriteS(const floatx4 (&acc)[RT][4], const float* __restrict__ cq, int go, int beo,
                  const float (*sst)[64][4], float invN,
                  unsigned short* act_, int colBase, int q, int ln){
  float mu[4], rs[4];
  #pragma unroll
  for (int ct=0;ct<4;ct++){
    int row = ct*16+ln;
    floatx4 s4 = *(const floatx4*)&sst[0][row][0];
    floatx4 q4 = *(const floatx4*)&sst[1][row][0];
    float sv = s4[0]+s4[1]+s4[2]+s4[3];
    float qv = q4[0]+q4[1]+q4[2]+q4[3];
    mu[ct] = sv*invN;
    rs[ct] = rsqrtf(qv*invN - mu[ct]*mu[ct] + 1e-5f);
  }
  #pragma unroll
  for (int rt=0;rt<RT;rt++){
    floatx4 g4  = *(const floatx4*)(cq + go  + rt*16 + q*4);
    floatx4 be4 = *(const floatx4*)(cq + beo + rt*16 + q*4);
    #pragma unroll
    for (int ct=0;ct<4;ct++){
      float y[4];
      #pragma unroll
      for (int r=0;r<4;r++)
        y[r] = fmaxf((acc[rt][ct][r]-mu[ct])*rs[ct]*g4[r]+be4[r], 0.f);
      uint2 pk; pk.x = pkbf(y[0],y[1]); pk.y = pkbf(y[2],y[3]);
      *(uint2*)(act_ + (ct*16+ln)*AST + colBase + rt*16 + q*4) = pk;
    }
  }
}

// =====================================================================
// fused forward: R1 skeleton, 7 barriers, prefetched weights, slot stats
// =====================================================================
__global__ __launch_bounds__(256,4) void dqn_main(
    const float* __restrict__ state, const float* __restrict__ td,
    const int* __restrict__ et, const unsigned short* __restrict__ wq,
    const float* __restrict__ cq, float* __restrict__ out)
{
  __shared__ __align__(16) unsigned short act[TM*AST];   // 33 KB
  __shared__ __align__(16) float sstat[2][64][4];        // per-wave stat slots 2 KB
  __shared__ float vbuf[64];

  const int tid=threadIdx.x, w=tid>>6, lane=tid&63, q=lane>>4, ln=lane&15;
  const int rowBlk = blockIdx.x*TM;
  const float* x0 = state + (size_t)rowBlk*199;

  const unsigned short* wl1 = wq + OFF_W1 + w*14336;
  const unsigned short* wl2 = wq + OFF_W2 + w*16384;
  const unsigned short* wl3 = wq + OFF_W3 + w*8192;
  const unsigned short* wlh = wq + OFF_WH + w*8192;
  const unsigned short* aBase = act + ln*AST + q*8;

  short8 pf[4];
  floatx4 acc[4][4];

  // ---- L1: x(224 incl bias row) -> h1(256), weights+acts straight from memory
  #pragma unroll
  for (int i=0;i<4;i++) pf[i] = *(const short8*)(wl1 + i*512 + lane*8);
  zeroAccT<4>(acc);
  gemmL1Gpf(acc, wl1, x0, td + rowBlk, lane, pf);
  statsS<4,false>(acc, cq, 0, sstat, w, q, ln);
  __syncthreads();                                        // B1

  #pragma unroll
  for (int i=0;i<4;i++) pf[i] = *(const short8*)(wl2 + i*512 + lane*8);  // prefetch W2 kc0
  lnWriteS<4>(acc, cq, C_G1+w*64, C_BE1+w*64, sstat, 1.f/256.f, act, w*64, q, ln);
  __syncthreads();                                        // B2

  // ---- L2: h1(256) -> h2(256) ----
  zeroAccT<4>(acc);
  runGemmPF<8,4>(acc, wl2, aBase, 0, lane, pf);
  statsS<4,true>(acc, cq, C_B2+w*64, sstat, w, q, ln);
  __syncthreads();                                        // B3

  #pragma unroll
  for (int i=0;i<4;i++) pf[i] = *(const short8*)(wl3 + i*512 + lane*8);  // prefetch W3 kc0-1
  lnWriteS<4>(acc, cq, C_G2+w*64, C_BE2+w*64, sstat, 1.f/256.f, act, w*64, q, ln);
  __syncthreads();                                        // B4

  // ---- L3: h2(256) -> f(128), wave n-cols [32w,32w+32) ----
  floatx4 acc3[2][4];
  zeroAccT<2>(acc3);
  runGemmPF<8,2>(acc3, wl3, aBase, 0, lane, pf);
  statsS<2,true>(acc3, cq, C_B3+w*32, sstat, w, q, ln);
  __syncthreads();                                        // B5

  #pragma unroll
  for (int i=0;i<4;i++) pf[i] = *(const short8*)(wlh + i*512 + lane*8);  // prefetch WH kc0
  lnWriteS<2>(acc3, cq, C_G3+w*32, C_BE3+w*32, sstat, 1.f/128.f, act, w*32, q, ln);
  __syncthreads();                                        // B6

  // ---- heads: wave w = head w (0..2 adv, 3 value). f(128)->64, LN in-wave ----
  zeroAccT<4>(acc);
  runGemmPF<4,4>(acc, wlh, aBase, 0, lane, pf);
  {
    const int bo = (w<3)? C_BA1+w*64 : C_BV1;
    const int go = (w<3)? C_GA +w*64 : C_GV;
    const int beo= (w<3)? C_BEA+w*64 : C_BEV;
    #pragma unroll
    for (int rt=0;rt<4;rt++){
      floatx4 b4 = *(const floatx4*)(cq + bo + rt*16 + q*4);
      #pragma unroll
      for (int ct=0;ct<4;ct++) acc[rt][ct] += b4;
    }
    float mu[4], rs[4];
    #pragma unroll
    for (int ct=0;ct<4;ct++){
      float s=0.f, ss=0.f;
      #pragma unroll
      for (int rt=0;rt<4;rt++)
        #pragma unroll
        for (int r=0;r<4;r++){ float v=acc[rt][ct][r]; s+=v; ss+=v*v; }
      s += __shfl_xor(s,16); ss += __shfl_xor(ss,16);
      s += __shfl_xor(s,32); ss += __shfl_xor(ss,32);
      mu[ct]=s*(1.f/64.f);
      rs[ct]=rsqrtf(ss*(1.f/64.f)-mu[ct]*mu[ct]+1e-5f);
    }
    #pragma unroll
    for (int rt=0;rt<4;rt++){
      floatx4 g4  = *(const floatx4*)(cq + go  + rt*16 + q*4);
      floatx4 be4 = *(const floatx4*)(cq + beo + rt*16 + q*4);
      #pragma unroll
      for (int ct=0;ct<4;ct++)
        #pragma unroll
        for (int r=0;r<4;r++)
          acc[rt][ct][r] = fmaxf((acc[rt][ct][r]-mu[ct])*rs[ct]*g4[r]+be4[r], 0.f);
    }
    if (w==3){
      float bv2v = cq[C_BV2];
      floatx4 wv4[4];
      #pragma unroll
      for (int rt=0;rt<4;rt++) wv4[rt] = *(const floatx4*)(cq + C_WV2 + rt*16 + q*4);
      #pragma unroll
      for (int ct=0;ct<4;ct++){
        float dot=0.f;
        #pragma unroll
        for (int rt=0;rt<4;rt++)
          #pragma unroll
          for (int r=0;r<4;r++) dot += acc[rt][ct][r]*wv4[rt][r];
        dot += __shfl_xor(dot,16);
        dot += __shfl_xor(dot,32);
        if (q==0) vbuf[ct*16+ln] = dot + bv2v;
      }
    }
  }
  __syncthreads();                                        // B7: head f-reads done; vbuf visible

  // adv heads: write ha into cols [64w,64w+64) (same-wave reuse), a2 GEMM, combine
  if (w<3){
    #pragma unroll
    for (int rt=0;rt<4;rt++)
      #pragma unroll
      for (int ct=0;ct<4;ct++){
        uint2 pk;
        pk.x = pkbf(acc[rt][ct][0], acc[rt][ct][1]);
        pk.y = pkbf(acc[rt][ct][2], acc[rt][ct][3]);
        *(uint2*)(act + (ct*16+ln)*AST + 64*w + rt*16 + q*4) = pk;
      }
    int ev[4];
    #pragma unroll
    for (int ct=0;ct<4;ct++) ev[ct] = et[rowBlk + ct*16 + ln];
    floatx4 acc2[2][4];
    zeroAccT<2>(acc2);
    runGemmW<2,2>(acc2, wq + OFF_WA2 + w*2048, aBase, 64*w, lane);
    #pragma unroll
    for (int rt=0;rt<2;rt++){
      floatx4 b4 = *(const floatx4*)(cq + C_BA2 + w*32 + rt*16 + q*4);
      #pragma unroll
      for (int ct=0;ct<4;ct++) acc2[rt][ct] += b4;
    }
    #pragma unroll
    for (int ct=0;ct<4;ct++){
      float sm=0.f;
      #pragma unroll
      for (int rt=0;rt<2;rt++)
        #pragma unroll
        for (int r=0;r<4;r++) sm += acc2[rt][ct][r];
      sm += __shfl_xor(sm,16);
      sm += __shfl_xor(sm,32);
      int b = ct*16+ln;
      if (ev[ct]==w){
        float vm = vbuf[b] - sm*(1.f/32.f);
        #pragma unroll
        for (int rt=0;rt<2;rt++){
          floatx4 o = acc2[rt][ct];
          o[0]+=vm; o[1]+=vm; o[2]+=vm; o[3]+=vm;
          *(floatx4*)(out + (size_t)(rowBlk+b)*32 + rt*16 + q*4) = o;
        }
      }
    }
  }
}

// =====================================================================
extern "C" void kernel_launch(void* const* d_in, const int* in_sizes, int n_in,
                              void* d_out, int out_size, void* d_ws, size_t ws_size,
                              hipStream_t stream)
{
  Ptrs p;
  p.state=(const float*)d_in[0];  p.td =(const float*)d_in[1];
  p.W1 =(const float*)d_in[2];  p.b1 =(const float*)d_in[3];  p.g1 =(const float*)d_in[4];  p.be1=(const float*)d_in[5];
  p.W2 =(const float*)d_in[6];  p.b2 =(const float*)d_in[7];  p.g2 =(const float*)d_in[8];  p.be2=(const float*)d_in[9];
  p.W3 =(const float*)d_in[10]; p.b3 =(const float*)d_in[11]; p.g3 =(const float*)d_in[12]; p.be3=(const float*)d_in[13];
  p.Wv1=(const float*)d_in[14]; p.bv1=(const float*)d_in[15]; p.gv =(const float*)d_in[16]; p.bev=(const float*)d_in[17];
  p.Wv2=(const float*)d_in[18]; p.bv2=(const float*)d_in[19];
  p.Wa1=(const float*)d_in[20]; p.ba1=(const float*)d_in[21]; p.ga =(const float*)d_in[22]; p.bea=(const float*)d_in[23];
  p.Wa2=(const float*)d_in[24]; p.ba2=(const float*)d_in[25];
  p.et =(const int*)d_in[26];

  unsigned short* wq = (unsigned short*)d_ws;
  float* cq = (float*)((char*)d_ws + (size_t)NWQ*2);

  const int prepN = NWQ + NCONST;
  hipLaunchKernelGGL(prep_kernel, dim3((prepN+255)/256), dim3(256), 0, stream, p, wq, cq);
  hipLaunchKernelGGL(dqn_main, dim3(NB/TM), dim3(256), 0, stream,
                     p.state, p.td, p.et, (const unsigned short*)wq, (const float*)cq, (float*)d_out);
}

// Round 7
// 289.310 us; speedup vs baseline: 1.0342x; 1.0342x over previous
//
#include <hip/hip_runtime.h>
#include <hip/hip_bf16.h>
#include <stdint.h>

#define DEV __device__ __forceinline__

typedef __attribute__((ext_vector_type(8))) short short8;    // 8 bf16 (MFMA A/B frag)
typedef __attribute__((ext_vector_type(4))) float floatx4;   // MFMA C/D frag

constexpr int TM  = 64;     // rows per block
constexpr int NB  = 131072; // batch
constexpr int AST = 264;    // act row stride (bf16 elems)

// ---- packed bf16 weight layout in d_ws (element offsets) ----
// A=weights, B=activations. Wave w owns a 64-col (L1/L2), 32-col (L3) n-slice.
constexpr int OFF_W1 = 0;        // 4w x 7kc x 4nt x 512   (K=224: 199 state + td@199 + BIAS@200)
constexpr int OFF_W2 = 57344;    // 4w x 8 x 4 x 512       (K=256, N=256)
constexpr int OFF_W3 = 122880;   // 4w x 8 x 2 x 512       (K=256, N=128)
constexpr int OFF_WH = 155648;   // 4h x 4 x 4 x 512       (K=128, N=64; h=0..2 adv, h=3 value)
constexpr int OFF_WA2= 188416;   // 3h x 2 x 2 x 512       (K=64,  N=32)
constexpr int NWQ    = 194560;

// cq layout: all float4-loadable bases 16B-aligned (verified R1 table)
constexpr int C_B1=0, C_G1=256, C_BE1=512, C_B2=768, C_G2=1024, C_BE2=1280,
  C_B3=1536, C_G3=1664, C_BE3=1792, C_BV1=1920, C_GV=1984, C_BEV=2048,
  C_WV2=2112, C_BV2=2176, C_BA1=2180, C_GA=2372, C_BEA=2564, C_BA2=2756;
constexpr int NCONST=2852;

struct Ptrs {
  const float *state,*td,*W1,*b1,*g1,*be1,*W2,*b2,*g2,*be2,*W3,*b3,*g3,*be3,
    *Wv1,*bv1,*gv,*bev,*Wv2,*bv2,*Wa1,*ba1,*ga,*bea,*Wa2,*ba2;
  const int *et;
};

DEV unsigned short f2bf(float x){
  uint32_t u = __float_as_uint(x);
  u += 0x7fffu + ((u>>16)&1u);
  return (unsigned short)(u>>16);
}
DEV uint32_t f2bf_pk(float a, float b){
  float2 f2; f2.x=a; f2.y=b;
  __hip_bfloat162 h = __float22bfloat162_rn(f2);
  union { __hip_bfloat162 h; uint32_t u; } cv; cv.h = h;
  return cv.u;
}

// keepalive: force the loaded fragment to be materialized HERE (pre-barrier).
DEV void keep8(const short8 &v){ asm volatile("" :: "v"(v)); }

// =====================================================================
// prep: quantize + transpose + pack weights (W1 carries b1 at k==200)
// (verified R1 packing + verified R1 cq table — unchanged)
// =====================================================================
__global__ void prep_kernel(Ptrs p, unsigned short* __restrict__ wq, float* __restrict__ cq){
  int idx = blockIdx.x*256 + threadIdx.x;
  if (idx < NWQ) {
    float v = 0.f;
    if (idx < OFF_W2) {                       // W1 (+bias row at k=200)
      int e = idx, w = e/14336, r = e%14336;
      int kc = r>>11, ct=(r>>9)&3, l=(r>>3)&63, j=r&7;
      int n = w*64 + ct*16 + (l&15);
      int k = kc*32 + (l>>4)*8 + j;
      if (k < 200) v = p.W1[k*256 + n];
      else if (k == 200) v = p.b1[n];
    } else if (idx < OFF_W3) {                // W2
      int e = idx-OFF_W2, w=e>>14, r=e&16383;
      int kc=r>>11, ct=(r>>9)&3, l=(r>>3)&63, j=r&7;
      int n = w*64 + ct*16 + (l&15);
      int k = kc*32 + (l>>4)*8 + j;
      v = p.W2[k*256 + n];
    } else if (idx < OFF_WH) {                // W3
      int e = idx-OFF_W3, w=e>>13, r=e&8191;
      int kc=r>>10, ct=(r>>9)&1, l=(r>>3)&63, j=r&7;
      int n = w*32 + ct*16 + (l&15);
      int k = kc*32 + (l>>4)*8 + j;
      v = p.W3[k*128 + n];
    } else if (idx < OFF_WA2) {               // Wv1/Wa1
      int e = idx-OFF_WH, h=e>>13, r=e&8191;
      int kc=r>>11, ct=(r>>9)&3, l=(r>>3)&63, j=r&7;
      int n = ct*16 + (l&15);
      int k = kc*32 + (l>>4)*8 + j;
      v = (h<3) ? p.Wa1[h*8192 + k*64 + n] : p.Wv1[k*64 + n];
    } else {                                  // Wa2
      int e = idx-OFF_WA2, h=e>>11, r=e&2047;
      int kc=r>>10, ct=(r>>9)&1, l=(r>>3)&63, j=r&7;
      int n = ct*16 + (l&15);
      int k = kc*32 + (l>>4)*8 + j;
      v = p.Wa2[h*2048 + k*32 + n];
    }
    wq[idx] = f2bf(v);
  } else if (idx < NWQ + NCONST) {
    int ci = idx - NWQ;
    float v;
    if      (ci < 256)  v = p.b1[ci];
    else if (ci < 512)  v = p.g1[ci-256];
    else if (ci < 768)  v = p.be1[ci-512];
    else if (ci < 1024) v = p.b2[ci-768];
    else if (ci < 1280) v = p.g2[ci-1024];
    else if (ci < 1536) v = p.be2[ci-1280];
    else if (ci < 1664) v = p.b3[ci-1536];
    else if (ci < 1792) v = p.g3[ci-1664];
    else if (ci < 1920) v = p.be3[ci-1792];
    else if (ci < 1984) v = p.bv1[ci-1920];
    else if (ci < 2048) v = p.gv[ci-1984];
    else if (ci < 2112) v = p.bev[ci-2048];
    else if (ci < 2176) v = p.Wv2[ci-2112];
    else if (ci < 2180) v = (ci==2176) ? p.bv2[0] : 0.f;   // bv2 + pad
    else if (ci < 2372) v = p.ba1[ci-2180];
    else if (ci < 2564) v = p.ga[ci-2372];
    else if (ci < 2756) v = p.bea[ci-2564];
    else                v = p.ba2[ci-2756];
    cq[ci] = v;
  }
}

// =====================================================================
// device helpers. C layout: col = batch row (lane&15), row = n = q*4+reg.
// =====================================================================
template<int RT>
DEV void zeroAccT(floatx4 (&acc)[RT][4]){
  const floatx4 z = {0.f,0.f,0.f,0.f};
  #pragma unroll
  for (int rt=0;rt<RT;rt++)
    #pragma unroll
    for (int ct=0;ct<4;ct++) acc[rt][ct]=z;
}

// GEMM: first 4 weight frags come prefetched (pf), rest load in-loop from L2.
// frag linear index = kc*RT + rt (same layout as verified R1).
template<int KC,int RT>
DEV void runGemmP(floatx4 (&acc)[RT][4], const unsigned short* __restrict__ wp,
                  const unsigned short* __restrict__ aB, int aOff, int lane,
                  const short8 (&pf)[4]){
  #pragma unroll
  for (int kc=0;kc<KC;kc++){
    short8 a[4];
    #pragma unroll
    for (int c=0;c<4;c++)
      a[c] = *(const short8*)(aB + c*16*AST + aOff + kc*32);
    #pragma unroll
    for (int rt=0;rt<RT;rt++){
      short8 bw;
      if constexpr (true){
        if (kc*RT+rt < 4) bw = pf[kc*RT+rt];
        else bw = *(const short8*)(wp + (kc*RT+rt)*512 + lane*8);
      }
      #pragma unroll
      for (int c=0;c<4;c++)
        acc[rt][c] = __builtin_amdgcn_mfma_f32_16x16x32_bf16(bw, a[c], acc[rt][c], 0,0,0);
    }
  }
}

// bias fold + per-batch-row (s,ss) -> per-wave slot store (no atomics, no init)
template<int RT,bool BIAS>
DEV void statsS(floatx4 (&acc)[RT][4], const float* __restrict__ cq, int bo,
                float (&sst)[2][64][4], int w, int q, int ln){
  if constexpr (BIAS){
    #pragma unroll
    for (int rt=0;rt<RT;rt++){
      floatx4 b4 = *(const floatx4*)(cq + bo + rt*16 + q*4);
      #pragma unroll
      for (int ct=0;ct<4;ct++) acc[rt][ct] += b4;
    }
  }
  #pragma unroll
  for (int ct=0;ct<4;ct++){
    float s=0.f, ss=0.f;
    #pragma unroll
    for (int rt=0;rt<RT;rt++)
      #pragma unroll
      for (int r=0;r<4;r++){ float v=acc[rt][ct][r]; s+=v; ss+=v*v; }
    s += __shfl_xor(s,16); ss += __shfl_xor(ss,16);
    s += __shfl_xor(s,32); ss += __shfl_xor(ss,32);
    if (q==0){
      sst[0][ct*16+ln][w] = s;
      sst[1][ct*16+ln][w] = ss;
    }
  }
}

// LN apply + relu + natural-order packed bf16 write; sums 4 per-wave partials
template<int RT>
DEV void lnWriteS(const floatx4 (&acc)[RT][4], const float* __restrict__ cq, int go, int beo,
                  const float (&sst)[2][64][4], float invN,
                  unsigned short* act_, int colBase, int q, int ln){
  float mu[4], rs[4];
  #pragma unroll
  for (int ct=0;ct<4;ct++){
    int row = ct*16+ln;
    floatx4 s4 = *(const floatx4*)&sst[0][row][0];
    floatx4 q4 = *(const floatx4*)&sst[1][row][0];
    float sv = (s4[0]+s4[1])+(s4[2]+s4[3]);
    float qv = (q4[0]+q4[1])+(q4[2]+q4[3]);
    mu[ct] = sv*invN;
    rs[ct] = rsqrtf(qv*invN - mu[ct]*mu[ct] + 1e-5f);
  }
  #pragma unroll
  for (int rt=0;rt<RT;rt++){
    floatx4 g4  = *(const floatx4*)(cq + go  + rt*16 + q*4);
    floatx4 be4 = *(const floatx4*)(cq + beo + rt*16 + q*4);
    #pragma unroll
    for (int ct=0;ct<4;ct++){
      float y[4];
      #pragma unroll
      for (int r=0;r<4;r++)
        y[r] = fmaxf((acc[rt][ct][r]-mu[ct])*rs[ct]*g4[r]+be4[r], 0.f);
      uint2 pk; pk.x = f2bf_pk(y[0],y[1]); pk.y = f2bf_pk(y[2],y[3]);
      *(uint2*)(act_ + (ct*16+ln)*AST + colBase + rt*16 + q*4) = pk;
    }
  }
}

// =====================================================================
// fused forward: R1 skeleton (8 barriers), keepalive-prefetched weights,
// slot stats. Everything else identical to the verified 128.6us kernel.
// =====================================================================
__global__ __launch_bounds__(256,4) void dqn_main(
    const float* __restrict__ state, const float* __restrict__ td,
    const int* __restrict__ et, const unsigned short* __restrict__ wq,
    const float* __restrict__ cq, float* __restrict__ out)
{
  __shared__ __align__(16) unsigned short act[TM*AST];   // 33 KB
  __shared__ __align__(16) float sstat[2][64][4];        // per-wave stat slots 2 KB
  __shared__ float vbuf[64];
  __shared__ int   etl[64];

  const int tid=threadIdx.x, w=tid>>6, lane=tid&63, q=lane>>4, ln=lane&15;
  const int rowBlk = blockIdx.x*TM;

  const unsigned short* wl1 = wq + OFF_W1 + w*14336;
  const unsigned short* wl2 = wq + OFF_W2 + w*16384;
  const unsigned short* wl3 = wq + OFF_W3 + w*8192;
  const unsigned short* wlh = wq + OFF_WH + w*8192;
  const unsigned short* aBase = act + ln*AST + q*8;

  short8 pf[4];

  // ---- prefetch W1 kc0 (oldest loads in queue), then stage x ----
  #pragma unroll
  for (int i=0;i<4;i++) pf[i] = *(const short8*)(wl1 + i*512 + lane*8);

  {
    const float* sbase = state + (size_t)rowBlk*199;
    #pragma unroll
    for (int it=0; it<7; ++it){
      int t = tid + it*256;
      int r = t/28, c = t - r*28;          // magic-div, once per 8 elems
      unsigned short* dst = act + r*AST + c*8;
      if (c < 25){
        const float* src = sbase + r*199 + c*8;
        float v0=src[0], v1=src[1], v2=src[2], v3=src[3];
        float v4=src[4], v5=src[5], v6=src[6];
        int o7 = (c==24)? 198 : c*8+7;     // avoid OOB speculation at row end
        float s7 = sbase[r*199 + o7];
        float v7 = (c==24)? td[rowBlk+r] : s7;
        uint4 pk;
        pk.x=f2bf_pk(v0,v1); pk.y=f2bf_pk(v2,v3);
        pk.z=f2bf_pk(v4,v5); pk.w=f2bf_pk(v6,v7);
        *(uint4*)dst = pk;
      } else {
        uint4 pk{0u,0u,0u,0u};
        if (c==25) pk.x = 0x3F80u;         // col 200 = bf16(1.0) * W1 bias row
        *(uint4*)dst = pk;
      }
    }
    if (tid < 64) etl[tid] = et[rowBlk+tid];
  }
  #pragma unroll
  for (int i=0;i<4;i++) keep8(pf[i]);      // W1 frags resident before B1
  __syncthreads();                                        // B1

  floatx4 acc[4][4];

  // ---- L1: x(224 incl bias row) -> h1(256) ----
  zeroAccT<4>(acc);
  runGemmP<7,4>(acc, wl1, aBase, 0, lane, pf);
  statsS<4,false>(acc, cq, 0, sstat, w, q, ln);
  __syncthreads();                                        // B2

  #pragma unroll
  for (int i=0;i<4;i++) pf[i] = *(const short8*)(wl2 + i*512 + lane*8);  // prefetch W2 kc0
  lnWriteS<4>(acc, cq, C_G1+w*64, C_BE1+w*64, sstat, 1.f/256.f, act, w*64, q, ln);
  #pragma unroll
  for (int i=0;i<4;i++) keep8(pf[i]);
  __syncthreads();                                        // B3

  // ---- L2: h1(256) -> h2(256) ----
  zeroAccT<4>(acc);
  runGemmP<8,4>(acc, wl2, aBase, 0, lane, pf);
  statsS<4,true>(acc, cq, C_B2+w*64, sstat, w, q, ln);
  __syncthreads();                                        // B4

  #pragma unroll
  for (int i=0;i<4;i++) pf[i] = *(const short8*)(wl3 + i*512 + lane*8);  // prefetch W3 kc0-1
  lnWriteS<4>(acc, cq, C_G2+w*64, C_BE2+w*64, sstat, 1.f/256.f, act, w*64, q, ln);
  #pragma unroll
  for (int i=0;i<4;i++) keep8(pf[i]);
  __syncthreads();                                        // B5

  // ---- L3: h2(256) -> f(128), wave n-cols [32w,32w+32) ----
  floatx4 acc3[2][4];
  zeroAccT<2>(acc3);
  runGemmP<8,2>(acc3, wl3, aBase, 0, lane, pf);
  statsS<2,true>(acc3, cq, C_B3+w*32, sstat, w, q, ln);
  __syncthreads();                                        // B6

  #pragma unroll
  for (int i=0;i<4;i++) pf[i] = *(const short8*)(wlh + i*512 + lane*8);  // prefetch WH kc0
  lnWriteS<2>(acc3, cq, C_G3+w*32, C_BE3+w*32, sstat, 1.f/128.f, act, w*32, q, ln);
  #pragma unroll
  for (int i=0;i<4;i++) keep8(pf[i]);
  __syncthreads();                                        // B7

  // ---- heads: wave w = head w (0..2 adv, 3 value). f(128)->64, LN in-wave ----
  short8 pfa[4];
  if (w<3){
    #pragma unroll
    for (int i=0;i<4;i++)
      pfa[i] = *(const short8*)(wq + OFF_WA2 + w*2048 + i*512 + lane*8);  // ALL a2 frags
  }
  zeroAccT<4>(acc);
  runGemmP<4,4>(acc, wlh, aBase, 0, lane, pf);
  {
    const int bo = (w<3)? C_BA1+w*64 : C_BV1;
    const int go = (w<3)? C_GA +w*64 : C_GV;
    const int beo= (w<3)? C_BEA+w*64 : C_BEV;
    #pragma unroll
    for (int rt=0;rt<4;rt++){
      floatx4 b4 = *(const floatx4*)(cq + bo + rt*16 + q*4);
      #pragma unroll
      for (int ct=0;ct<4;ct++) acc[rt][ct] += b4;
    }
    float mu[4], rs[4];
    #pragma unroll
    for (int ct=0;ct<4;ct++){
      float s=0.f, ss=0.f;
      #pragma unroll
      for (int rt=0;rt<4;rt++)
        #pragma unroll
        for (int r=0;r<4;r++){ float v=acc[rt][ct][r]; s+=v; ss+=v*v; }
      s += __shfl_xor(s,16); ss += __shfl_xor(ss,16);
      s += __shfl_xor(s,32); ss += __shfl_xor(ss,32);
      mu[ct]=s*(1.f/64.f);
      rs[ct]=rsqrtf(ss*(1.f/64.f)-mu[ct]*mu[ct]+1e-5f);
    }
    #pragma unroll
    for (int rt=0;rt<4;rt++){
      floatx4 g4  = *(const floatx4*)(cq + go  + rt*16 + q*4);
      floatx4 be4 = *(const floatx4*)(cq + beo + rt*16 + q*4);
      #pragma unroll
      for (int ct=0;ct<4;ct++)
        #pragma unroll
        for (int r=0;r<4;r++)
          acc[rt][ct][r] = fmaxf((acc[rt][ct][r]-mu[ct])*rs[ct]*g4[r]+be4[r], 0.f);
    }
    if (w==3){
      float bv2v = cq[C_BV2];
      floatx4 wv4[4];
      #pragma unroll
      for (int rt=0;rt<4;rt++) wv4[rt] = *(const floatx4*)(cq + C_WV2 + rt*16 + q*4);
      #pragma unroll
      for (int ct=0;ct<4;ct++){
        float dot=0.f;
        #pragma unroll
        for (int rt=0;rt<4;rt++)
          #pragma unroll
          for (int r=0;r<4;r++) dot += acc[rt][ct][r]*wv4[rt][r];
        dot += __shfl_xor(dot,16);
        dot += __shfl_xor(dot,32);
        if (q==0) vbuf[ct*16+ln] = dot + bv2v;
      }
    }
  }
  if (w<3){
    #pragma unroll
    for (int i=0;i<4;i++) keep8(pfa[i]);   // a2 frags resident before B8
  }
  __syncthreads();                                        // B8: f-reads done; vbuf visible

  // adv heads: write ha into cols [64w,64w+64) (same-wave reuse), a2 GEMM, combine
  if (w<3){
    #pragma unroll
    for (int rt=0;rt<4;rt++)
      #pragma unroll
      for (int ct=0;ct<4;ct++){
        uint2 pk;
        pk.x = f2bf_pk(acc[rt][ct][0], acc[rt][ct][1]);
        pk.y = f2bf_pk(acc[rt][ct][2], acc[rt][ct][3]);
        *(uint2*)(act + (ct*16+ln)*AST + 64*w + rt*16 + q*4) = pk;
      }
    floatx4 acc2[2][4];
    zeroAccT<2>(acc2);
    #pragma unroll
    for (int kc=0;kc<2;kc++){
      short8 a[4];
      #pragma unroll
      for (int c=0;c<4;c++)
        a[c] = *(const short8*)(aBase + c*16*AST + 64*w + kc*32);
      #pragma unroll
      for (int rt=0;rt<2;rt++)
        #pragma unroll
        for (int c=0;c<4;c++)
          acc2[rt][c] = __builtin_amdgcn_mfma_f32_16x16x32_bf16(pfa[kc*2+rt], a[c], acc2[rt][c], 0,0,0);
    }
    #pragma unroll
    for (int rt=0;rt<2;rt++){
      floatx4 b4 = *(const floatx4*)(cq + C_BA2 + w*32 + rt*16 + q*4);
      #pragma unroll
      for (int ct=0;ct<4;ct++) acc2[rt][ct] += b4;
    }
    #pragma unroll
    for (int ct=0;ct<4;ct++){
      float sm=0.f;
      #pragma unroll
      for (int rt=0;rt<2;rt++)
        #pragma unroll
        for (int r=0;r<4;r++) sm += acc2[rt][ct][r];
      sm += __shfl_xor(sm,16);
      sm += __shfl_xor(sm,32);
      int b = ct*16+ln;
      if (etl[b]==w){
        float vm = vbuf[b] - sm*(1.f/32.f);
        #pragma unroll
        for (int rt=0;rt<2;rt++){
          floatx4 o = acc2[rt][ct];
          o[0]+=vm; o[1]+=vm; o[2]+=vm; o[3]+=vm;
          *(floatx4*)(out + (size_t)(rowBlk+b)*32 + rt*16 + q*4) = o;
        }
      }
    }
  }
}

// =====================================================================
extern "C" void kernel_launch(void* const* d_in, const int* in_sizes, int n_in,
                              void* d_out, int out_size, void* d_ws, size_t ws_size,
                              hipStream_t stream)
{
  Ptrs p;
  p.state=(const float*)d_in[0];  p.td =(const float*)d_in[1];
  p.W1 =(const float*)d_in[2];  p.b1 =(const float*)d_in[3];  p.g1 =(const float*)d_in[4];  p.be1=(const float*)d_in[5];
  p.W2 =(const float*)d_in[6];  p.b2 =(const float*)d_in[7];  p.g2 =(const float*)d_in[8];  p.be2=(const float*)d_in[9];
  p.W3 =(const float*)d_in[10]; p.b3 =(const float*)d_in[11]; p.g3 =(const float*)d_in[12]; p.be3=(const float*)d_in[13];
  p.Wv1=(const float*)d_in[14]; p.bv1=(const float*)d_in[15]; p.gv =(const float*)d_in[16]; p.bev=(const float*)d_in[17];
  p.Wv2=(const float*)d_in[18]; p.bv2=(const float*)d_in[19];
  p.Wa1=(const float*)d_in[20]; p.ba1=(const float*)d_in[21]; p.ga =(const float*)d_in[22]; p.bea=(const float*)d_in[23];
  p.Wa2=(const float*)d_in[24]; p.ba2=(const float*)d_in[25];
  p.et =(const int*)d_in[26];

  unsigned short* wq = (unsigned short*)d_ws;
  float* cq = (float*)((char*)d_ws + (size_t)NWQ*2);

  const int prepN = NWQ + NCONST;
  hipLaunchKernelGGL(prep_kernel, dim3((prepN+255)/256), dim3(256), 0, stream, p, wq, cq);
  hipLaunchKernelGGL(dqn_main, dim3(NB/TM), dim3(256), 0, stream,
                     p.state, p.td, p.et, (const unsigned short*)wq, (const float*)cq, (float*)d_out);
}

// Round 8
// 274.176 us; speedup vs baseline: 1.0913x; 1.0552x over previous
//
#include <hip/hip_runtime.h>
#include <hip/hip_bf16.h>
#include <stdint.h>

#define DEV __device__ __forceinline__

typedef __attribute__((ext_vector_type(8))) short short8;    // 8 bf16 (MFMA A/B frag)
typedef __attribute__((ext_vector_type(4))) float floatx4;   // MFMA C/D frag

constexpr int TM  = 64;     // rows per block
constexpr int NB  = 131072; // batch
constexpr int AST = 264;    // act row stride (bf16 elems)

// ---- packed bf16 weight layout in d_ws (element offsets) ----
// A=weights, B=activations. Wave w owns a 64-col (L1/L2), 32-col (L3) n-slice.
constexpr int OFF_W1 = 0;        // 4w x 7kc x 4nt x 512   (K=224: 199 state + td@199 + BIAS@200)
constexpr int OFF_W2 = 57344;    // 4w x 8 x 4 x 512       (K=256, N=256)
constexpr int OFF_W3 = 122880;   // 4w x 8 x 2 x 512       (K=256, N=128)
constexpr int OFF_WH = 155648;   // 4h x 4 x 4 x 512       (K=128, N=64; h=0..2 adv, h=3 value)
constexpr int OFF_WA2= 188416;   // 3h x 2 x 2 x 512       (K=64,  N=32)
constexpr int NWQ    = 194560;

// cq layout: all float4-loadable bases 16B-aligned (verified R1 table)
constexpr int C_B1=0, C_G1=256, C_BE1=512, C_B2=768, C_G2=1024, C_BE2=1280,
  C_B3=1536, C_G3=1664, C_BE3=1792, C_BV1=1920, C_GV=1984, C_BEV=2048,
  C_WV2=2112, C_BV2=2176, C_BA1=2180, C_GA=2372, C_BEA=2564, C_BA2=2756;
constexpr int NCONST=2852;

struct Ptrs {
  const float *state,*td,*W1,*b1,*g1,*be1,*W2,*b2,*g2,*be2,*W3,*b3,*g3,*be3,
    *Wv1,*bv1,*gv,*bev,*Wv2,*bv2,*Wa1,*ba1,*ga,*bea,*Wa2,*ba2;
  const int *et;
};

DEV unsigned short f2bf(float x){
  uint32_t u = __float_as_uint(x);
  u += 0x7fffu + ((u>>16)&1u);
  return (unsigned short)(u>>16);
}
DEV uint32_t f2bf_pk(float a, float b){
  float2 f2; f2.x=a; f2.y=b;
  __hip_bfloat162 h = __float22bfloat162_rn(f2);
  union { __hip_bfloat162 h; uint32_t u; } cv; cv.h = h;
  return cv.u;
}

// =====================================================================
// prep: quantize + transpose + pack weights (W1 carries b1 at k==200)
// (verified R1 packing + verified R1 cq table — unchanged)
// =====================================================================
__global__ void prep_kernel(Ptrs p, unsigned short* __restrict__ wq, float* __restrict__ cq){
  int idx = blockIdx.x*256 + threadIdx.x;
  if (idx < NWQ) {
    float v = 0.f;
    if (idx < OFF_W2) {                       // W1 (+bias row at k=200)
      int e = idx, w = e/14336, r = e%14336;
      int kc = r>>11, ct=(r>>9)&3, l=(r>>3)&63, j=r&7;
      int n = w*64 + ct*16 + (l&15);
      int k = kc*32 + (l>>4)*8 + j;
      if (k < 200) v = p.W1[k*256 + n];
      else if (k == 200) v = p.b1[n];
    } else if (idx < OFF_W3) {                // W2
      int e = idx-OFF_W2, w=e>>14, r=e&16383;
      int kc=r>>11, ct=(r>>9)&3, l=(r>>3)&63, j=r&7;
      int n = w*64 + ct*16 + (l&15);
      int k = kc*32 + (l>>4)*8 + j;
      v = p.W2[k*256 + n];
    } else if (idx < OFF_WH) {                // W3
      int e = idx-OFF_W3, w=e>>13, r=e&8191;
      int kc=r>>10, ct=(r>>9)&1, l=(r>>3)&63, j=r&7;
      int n = w*32 + ct*16 + (l&15);
      int k = kc*32 + (l>>4)*8 + j;
      v = p.W3[k*128 + n];
    } else if (idx < OFF_WA2) {               // Wv1/Wa1
      int e = idx-OFF_WH, h=e>>13, r=e&8191;
      int kc=r>>11, ct=(r>>9)&3, l=(r>>3)&63, j=r&7;
      int n = ct*16 + (l&15);
      int k = kc*32 + (l>>4)*8 + j;
      v = (h<3) ? p.Wa1[h*8192 + k*64 + n] : p.Wv1[k*64 + n];
    } else {                                  // Wa2
      int e = idx-OFF_WA2, h=e>>11, r=e&2047;
      int kc=r>>10, ct=(r>>9)&1, l=(r>>3)&63, j=r&7;
      int n = ct*16 + (l&15);
      int k = kc*32 + (l>>4)*8 + j;
      v = p.Wa2[h*2048 + k*32 + n];
    }
    wq[idx] = f2bf(v);
  } else if (idx < NWQ + NCONST) {
    int ci = idx - NWQ;
    float v;
    if      (ci < 256)  v = p.b1[ci];
    else if (ci < 512)  v = p.g1[ci-256];
    else if (ci < 768)  v = p.be1[ci-512];
    else if (ci < 1024) v = p.b2[ci-768];
    else if (ci < 1280) v = p.g2[ci-1024];
    else if (ci < 1536) v = p.be2[ci-1280];
    else if (ci < 1664) v = p.b3[ci-1536];
    else if (ci < 1792) v = p.g3[ci-1664];
    else if (ci < 1920) v = p.be3[ci-1792];
    else if (ci < 1984) v = p.bv1[ci-1920];
    else if (ci < 2048) v = p.gv[ci-1984];
    else if (ci < 2112) v = p.bev[ci-2048];
    else if (ci < 2176) v = p.Wv2[ci-2112];
    else if (ci < 2180) v = (ci==2176) ? p.bv2[0] : 0.f;   // bv2 + pad
    else if (ci < 2372) v = p.ba1[ci-2180];
    else if (ci < 2564) v = p.ga[ci-2372];
    else if (ci < 2756) v = p.bea[ci-2564];
    else                v = p.ba2[ci-2756];
    cq[ci] = v;
  }
}

// =====================================================================
// device helpers. C layout: col = batch row (lane&15), row = n = q*4+reg.
// =====================================================================
template<int RT>
DEV void zeroAccT(floatx4 (&acc)[RT][4]){
  const floatx4 z = {0.f,0.f,0.f,0.f};
  #pragma unroll
  for (int rt=0;rt<RT;rt++)
    #pragma unroll
    for (int ct=0;ct<4;ct++) acc[rt][ct]=z;
}

// init accumulators with the bias (MFMA C-in carries it; deletes bias-add pass)
template<int RT>
DEV void biasAccT(floatx4 (&acc)[RT][4], const float* __restrict__ cqb, int q){
  #pragma unroll
  for (int rt=0;rt<RT;rt++){
    floatx4 b4 = *(const floatx4*)(cqb + rt*16 + q*4);
    #pragma unroll
    for (int ct=0;ct<4;ct++) acc[rt][ct]=b4;
  }
}

// streaming-weight GEMM (verified R1 form; weights pipelined by compiler)
template<int KC,int RT>
DEV void runGemmW(floatx4 (&acc)[RT][4], const unsigned short* __restrict__ wp,
                  const unsigned short* __restrict__ aB, int aOff, int lane){
  __builtin_amdgcn_s_setprio(1);
  #pragma unroll
  for (int kc=0;kc<KC;kc++){
    short8 a[4];
    #pragma unroll
    for (int c=0;c<4;c++)
      a[c] = *(const short8*)(aB + c*16*AST + aOff + kc*32);
    #pragma unroll
    for (int rt=0;rt<RT;rt++){
      short8 bw = *(const short8*)(wp + (kc*RT+rt)*512 + lane*8);
      #pragma unroll
      for (int c=0;c<4;c++)
        acc[rt][c] = __builtin_amdgcn_mfma_f32_16x16x32_bf16(bw, a[c], acc[rt][c], 0,0,0);
    }
  }
  __builtin_amdgcn_s_setprio(0);
}

// per-batch-row (s,ss) -> per-wave slot store (no atomics, no init needed)
template<int RT>
DEV void statsS(const floatx4 (&acc)[RT][4],
                float (&sst)[2][64][4], int w, int q, int ln){
  #pragma unroll
  for (int ct=0;ct<4;ct++){
    float s=0.f, ss=0.f;
    #pragma unroll
    for (int rt=0;rt<RT;rt++)
      #pragma unroll
      for (int r=0;r<4;r++){ float v=acc[rt][ct][r]; s+=v; ss+=v*v; }
    s += __shfl_xor(s,16); ss += __shfl_xor(ss,16);
    s += __shfl_xor(s,32); ss += __shfl_xor(ss,32);
    if (q==0){
      sst[0][ct*16+ln][w] = s;
      sst[1][ct*16+ln][w] = ss;
    }
  }
}

// LN apply + relu + natural-order packed bf16 write; sums 4 per-wave partials
template<int RT>
DEV void lnWriteS(const floatx4 (&acc)[RT][4], const float* __restrict__ cq, int go, int beo,
                  const float (&sst)[2][64][4], float invN,
                  unsigned short* act_, int colBase, int q, int ln){
  float mu[4], rs[4];
  #pragma unroll
  for (int ct=0;ct<4;ct++){
    int row = ct*16+ln;
    floatx4 s4 = *(const floatx4*)&sst[0][row][0];
    floatx4 q4 = *(const floatx4*)&sst[1][row][0];
    float sv = (s4[0]+s4[1])+(s4[2]+s4[3]);
    float qv = (q4[0]+q4[1])+(q4[2]+q4[3]);
    mu[ct] = sv*invN;
    rs[ct] = rsqrtf(qv*invN - mu[ct]*mu[ct] + 1e-5f);
  }
  #pragma unroll
  for (int rt=0;rt<RT;rt++){
    floatx4 g4  = *(const floatx4*)(cq + go  + rt*16 + q*4);
    floatx4 be4 = *(const floatx4*)(cq + beo + rt*16 + q*4);
    #pragma unroll
    for (int ct=0;ct<4;ct++){
      float y[4];
      #pragma unroll
      for (int r=0;r<4;r++)
        y[r] = fmaxf((acc[rt][ct][r]-mu[ct])*rs[ct]*g4[r]+be4[r], 0.f);
      uint2 pk; pk.x = f2bf_pk(y[0],y[1]); pk.y = f2bf_pk(y[2],y[3]);
      *(uint2*)(act_ + (ct*16+ln)*AST + colBase + rt*16 + q*4) = pk;
    }
  }
}

// =====================================================================
// fused forward: R1 skeleton (8 barriers), bias-in-acc, slot stats, setprio
// =====================================================================
__global__ __launch_bounds__(256,4) void dqn_main(
    const float* __restrict__ state, const float* __restrict__ td,
    const int* __restrict__ et, const unsigned short* __restrict__ wq,
    const float* __restrict__ cq, float* __restrict__ out)
{
  __shared__ __align__(16) unsigned short act[TM*AST];   // 33 KB
  __shared__ __align__(16) float sstat[2][64][4];        // per-wave stat slots 2 KB
  __shared__ float vbuf[64];
  __shared__ int   etl[64];

  const int tid=threadIdx.x, w=tid>>6, lane=tid&63, q=lane>>4, ln=lane&15;
  const int rowBlk = blockIdx.x*TM;

  const unsigned short* wl1 = wq + OFF_W1 + w*14336;
  const unsigned short* wl2 = wq + OFF_W2 + w*16384;
  const unsigned short* wl3 = wq + OFF_W3 + w*8192;
  const unsigned short* wlh = wq + OFF_WH + w*8192;
  const unsigned short* aBase = act + ln*AST + q*8;

  // ---- stage x = [state(199) | td@199 | 1.0@200 | 0 pad to 223] (R1 exact) ----
  {
    const float* sbase = state + (size_t)rowBlk*199;
    #pragma unroll
    for (int it=0; it<7; ++it){
      int t = tid + it*256;
      int r = t/28, c = t - r*28;          // magic-div, once per 8 elems
      unsigned short* dst = act + r*AST + c*8;
      if (c < 25){
        const float* src = sbase + r*199 + c*8;
        float v0=src[0], v1=src[1], v2=src[2], v3=src[3];
        float v4=src[4], v5=src[5], v6=src[6];
        int o7 = (c==24)? 198 : c*8+7;     // avoid OOB speculation at row end
        float s7 = sbase[r*199 + o7];
        float v7 = (c==24)? td[rowBlk+r] : s7;
        uint4 pk;
        pk.x=f2bf_pk(v0,v1); pk.y=f2bf_pk(v2,v3);
        pk.z=f2bf_pk(v4,v5); pk.w=f2bf_pk(v6,v7);
        *(uint4*)dst = pk;
      } else {
        uint4 pk{0u,0u,0u,0u};
        if (c==25) pk.x = 0x3F80u;         // col 200 = bf16(1.0) * W1 bias row
        *(uint4*)dst = pk;
      }
    }
    if (tid < 64) etl[tid] = et[rowBlk+tid];
  }
  __syncthreads();                                        // B1

  floatx4 acc[4][4];

  // ---- L1: x(224 incl bias row) -> h1(256); bias via k=200 row ----
  zeroAccT<4>(acc);
  runGemmW<7,4>(acc, wl1, aBase, 0, lane);
  statsS<4>(acc, sstat, w, q, ln);
  __syncthreads();                                        // B2
  lnWriteS<4>(acc, cq, C_G1+w*64, C_BE1+w*64, sstat, 1.f/256.f, act, w*64, q, ln);
  __syncthreads();                                        // B3

  // ---- L2: h1(256) -> h2(256); bias in acc init ----
  biasAccT<4>(acc, cq + C_B2 + w*64, q);
  runGemmW<8,4>(acc, wl2, aBase, 0, lane);
  statsS<4>(acc, sstat, w, q, ln);
  __syncthreads();                                        // B4
  lnWriteS<4>(acc, cq, C_G2+w*64, C_BE2+w*64, sstat, 1.f/256.f, act, w*64, q, ln);
  __syncthreads();                                        // B5

  // ---- L3: h2(256) -> f(128), wave n-cols [32w,32w+32) ----
  floatx4 acc3[2][4];
  biasAccT<2>(acc3, cq + C_B3 + w*32, q);
  runGemmW<8,2>(acc3, wl3, aBase, 0, lane);
  statsS<2>(acc3, sstat, w, q, ln);
  __syncthreads();                                        // B6
  lnWriteS<2>(acc3, cq, C_G3+w*32, C_BE3+w*32, sstat, 1.f/128.f, act, w*32, q, ln);
  __syncthreads();                                        // B7

  // ---- heads: wave w = head w (0..2 adv, 3 value). f(128)->64, LN in-wave ----
  const int bo = (w<3)? C_BA1+w*64 : C_BV1;
  const int go = (w<3)? C_GA +w*64 : C_GV;
  const int beo= (w<3)? C_BEA+w*64 : C_BEV;
  biasAccT<4>(acc, cq + bo, q);
  runGemmW<4,4>(acc, wlh, aBase, 0, lane);
  {
    float mu[4], rs[4];
    #pragma unroll
    for (int ct=0;ct<4;ct++){
      float s=0.f, ss=0.f;
      #pragma unroll
      for (int rt=0;rt<4;rt++)
        #pragma unroll
        for (int r=0;r<4;r++){ float v=acc[rt][ct][r]; s+=v; ss+=v*v; }
      s += __shfl_xor(s,16); ss += __shfl_xor(ss,16);
      s += __shfl_xor(s,32); ss += __shfl_xor(ss,32);
      mu[ct]=s*(1.f/64.f);
      rs[ct]=rsqrtf(ss*(1.f/64.f)-mu[ct]*mu[ct]+1e-5f);
    }
    #pragma unroll
    for (int rt=0;rt<4;rt++){
      floatx4 g4  = *(const floatx4*)(cq + go  + rt*16 + q*4);
      floatx4 be4 = *(const floatx4*)(cq + beo + rt*16 + q*4);
      #pragma unroll
      for (int ct=0;ct<4;ct++)
        #pragma unroll
        for (int r=0;r<4;r++)
          acc[rt][ct][r] = fmaxf((acc[rt][ct][r]-mu[ct])*rs[ct]*g4[r]+be4[r], 0.f);
    }
    if (w==3){
      float bv2v = cq[C_BV2];
      floatx4 wv4[4];
      #pragma unroll
      for (int rt=0;rt<4;rt++) wv4[rt] = *(const floatx4*)(cq + C_WV2 + rt*16 + q*4);
      #pragma unroll
      for (int ct=0;ct<4;ct++){
        float dot=0.f;
        #pragma unroll
        for (int rt=0;rt<4;rt++)
          #pragma unroll
          for (int r=0;r<4;r++) dot += acc[rt][ct][r]*wv4[rt][r];
        dot += __shfl_xor(dot,16);
        dot += __shfl_xor(dot,32);
        if (q==0) vbuf[ct*16+ln] = dot + bv2v;
      }
    }
  }
  __syncthreads();                                        // B8: f-reads done; vbuf visible

  // adv heads: write ha into cols [64w,64w+64) (same-wave reuse), a2 GEMM, combine
  if (w<3){
    #pragma unroll
    for (int rt=0;rt<4;rt++)
      #pragma unroll
      for (int ct=0;ct<4;ct++){
        uint2 pk;
        pk.x = f2bf_pk(acc[rt][ct][0], acc[rt][ct][1]);
        pk.y = f2bf_pk(acc[rt][ct][2], acc[rt][ct][3]);
        *(uint2*)(act + (ct*16+ln)*AST + 64*w + rt*16 + q*4) = pk;
      }
    floatx4 acc2[2][4];
    biasAccT<2>(acc2, cq + C_BA2 + w*32, q);
    runGemmW<2,2>(acc2, wq + OFF_WA2 + w*2048, aBase, 64*w, lane);
    #pragma unroll
    for (int ct=0;ct<4;ct++){
      float sm=0.f;
      #pragma unroll
      for (int rt=0;rt<2;rt++)
        #pragma unroll
        for (int r=0;r<4;r++) sm += acc2[rt][ct][r];
      sm += __shfl_xor(sm,16);
      sm += __shfl_xor(sm,32);
      int b = ct*16+ln;
      if (etl[b]==w){
        float vm = vbuf[b] - sm*(1.f/32.f);
        #pragma unroll
        for (int rt=0;rt<2;rt++){
          floatx4 o = acc2[rt][ct];
          o[0]+=vm; o[1]+=vm; o[2]+=vm; o[3]+=vm;
          *(floatx4*)(out + (size_t)(rowBlk+b)*32 + rt*16 + q*4) = o;
        }
      }
    }
  }
}

// =====================================================================
extern "C" void kernel_launch(void* const* d_in, const int* in_sizes, int n_in,
                              void* d_out, int out_size, void* d_ws, size_t ws_size,
                              hipStream_t stream)
{
  Ptrs p;
  p.state=(const float*)d_in[0];  p.td =(const float*)d_in[1];
  p.W1 =(const float*)d_in[2];  p.b1 =(const float*)d_in[3];  p.g1 =(const float*)d_in[4];  p.be1=(const float*)d_in[5];
  p.W2 =(const float*)d_in[6];  p.b2 =(const float*)d_in[7];  p.g2 =(const float*)d_in[8];  p.be2=(const float*)d_in[9];
  p.W3 =(const float*)d_in[10]; p.b3 =(const float*)d_in[11]; p.g3 =(const float*)d_in[12]; p.be3=(const float*)d_in[13];
  p.Wv1=(const float*)d_in[14]; p.bv1=(const float*)d_in[15]; p.gv =(const float*)d_in[16]; p.bev=(const float*)d_in[17];
  p.Wv2=(const float*)d_in[18]; p.bv2=(const float*)d_in[19];
  p.Wa1=(const float*)d_in[20]; p.ba1=(const float*)d_in[21]; p.ga =(const float*)d_in[22]; p.bea=(const float*)d_in[23];
  p.Wa2=(const float*)d_in[24]; p.ba2=(const float*)d_in[25];
  p.et =(const int*)d_in[26];

  unsigned short* wq = (unsigned short*)d_ws;
  float* cq = (float*)((char*)d_ws + (size_t)NWQ*2);

  const int prepN = NWQ + NCONST;
  hipLaunchKernelGGL(prep_kernel, dim3((prepN+255)/256), dim3(256), 0, stream, p, wq, cq);
  hipLaunchKernelGGL(dqn_main, dim3(NB/TM), dim3(256), 0, stream,
                     p.state, p.td, p.et, (const unsigned short*)wq, (const float*)cq, (float*)d_out);
}